// Round 1
// baseline (303.465 us; speedup 1.0000x reference)
//
#include <hip/hip_runtime.h>

// out[b,f] = x0[b,f] * dot(x[b,:], w) + bias[f] + x[b,f]
// B = 16384 rows, F = 2048 cols, fp32 throughout.
// One 256-thread block per row; each thread owns vec4 slots t and t+256
// (F/4 = 512 float4 slots per row). x row is loaded once into registers,
// reused for both the dot-product and the output epilogue.

#define F_DIM 2048

__global__ __launch_bounds__(256) void cross_row_kernel(
    const float* __restrict__ x0,
    const float* __restrict__ x,
    const float* __restrict__ w,
    const float* __restrict__ bias,
    float* __restrict__ out)
{
    const int b = blockIdx.x;
    const int t = threadIdx.x;
    const long long row = (long long)b * F_DIM;

    const float4* __restrict__ x4  = (const float4*)(x  + row);
    const float4* __restrict__ x04 = (const float4*)(x0 + row);
    const float4* __restrict__ w4  = (const float4*)w;
    const float4* __restrict__ bi4 = (const float4*)bias;
    float4* __restrict__ o4 = (float4*)(out + row);

    // Load x row (registers) + weights.
    float4 xa = x4[t];
    float4 xb = x4[t + 256];
    float4 wa = w4[t];
    float4 wb = w4[t + 256];

    // Kick off the epilogue loads early so they're in flight during the
    // reduction (independent of the dot).
    float4 x0a = x04[t];
    float4 x0b = x04[t + 256];
    float4 ba  = bi4[t];
    float4 bb  = bi4[t + 256];

    float partial = xa.x * wa.x + xa.y * wa.y + xa.z * wa.z + xa.w * wa.w
                  + xb.x * wb.x + xb.y * wb.y + xb.z * wb.z + xb.w * wb.w;

    // Wave-level butterfly reduce over 64 lanes.
    #pragma unroll
    for (int off = 32; off > 0; off >>= 1)
        partial += __shfl_down(partial, off, 64);

    __shared__ float sdot[4];
    __shared__ float dot_s;
    const int wave = t >> 6;
    const int lane = t & 63;
    if (lane == 0) sdot[wave] = partial;
    __syncthreads();
    if (t == 0) dot_s = sdot[0] + sdot[1] + sdot[2] + sdot[3];
    __syncthreads();
    const float dot = dot_s;

    float4 oa, ob;
    oa.x = x0a.x * dot + ba.x + xa.x;
    oa.y = x0a.y * dot + ba.y + xa.y;
    oa.z = x0a.z * dot + ba.z + xa.z;
    oa.w = x0a.w * dot + ba.w + xa.w;
    ob.x = x0b.x * dot + bb.x + xb.x;
    ob.y = x0b.y * dot + bb.y + xb.y;
    ob.z = x0b.z * dot + bb.z + xb.z;
    ob.w = x0b.w * dot + bb.w + xb.w;

    o4[t]       = oa;
    o4[t + 256] = ob;
}

extern "C" void kernel_launch(void* const* d_in, const int* in_sizes, int n_in,
                              void* d_out, int out_size, void* d_ws, size_t ws_size,
                              hipStream_t stream) {
    const float* x0   = (const float*)d_in[0];
    const float* x    = (const float*)d_in[1];
    const float* w    = (const float*)d_in[2];
    const float* bias = (const float*)d_in[3];
    float* out = (float*)d_out;

    const int B = in_sizes[0] / F_DIM;  // 16384
    cross_row_kernel<<<B, 256, 0, stream>>>(x0, x, w, bias, out);
}